// Round 10
// baseline (241.816 us; speedup 1.0000x reference)
//
#include <hip/hip_runtime.h>
#include <hip/hip_bf16.h>

#define B_ 8
#define T_ 1024
#define C_ 1024
#define H_ 16
#define D_ 64
#define QKVLD 3072  // H_*3*D_

typedef short v4s __attribute__((ext_vector_type(4)));
typedef short v8s __attribute__((ext_vector_type(8)));
typedef float v4f __attribute__((ext_vector_type(4)));
typedef float v16f __attribute__((ext_vector_type(16)));

__device__ __forceinline__ unsigned short f2b(float f) {
    unsigned int u = __builtin_bit_cast(unsigned int, f);
    unsigned int lsb = (u >> 16) & 1u;
    u += 0x7fffu + lsb;
    return (unsigned short)(u >> 16);
}

__device__ __forceinline__ float fexp2(float x) {
    return __expf(x * 0.69314718056f);   // compiler folds to v_exp_f32
}

// pack 4 fp32 -> 4 bf16 (round-half-up; inputs are P in [0,1], no NaN/neg)
__device__ __forceinline__ v4s pack4(float p0, float p1, float p2, float p3) {
    unsigned int a = (__builtin_bit_cast(unsigned int, p0) + 0x8000u) >> 16;
    unsigned int b = (__builtin_bit_cast(unsigned int, p1) + 0x8000u) & 0xFFFF0000u;
    unsigned int c = (__builtin_bit_cast(unsigned int, p2) + 0x8000u) >> 16;
    unsigned int d = (__builtin_bit_cast(unsigned int, p3) + 0x8000u) & 0xFFFF0000u;
    union { unsigned int u[2]; v4s v; } t;
    t.u[0] = a | b; t.u[1] = c | d;
    return t.v;
}

#define MFMA32(A, B, C) __builtin_amdgcn_mfma_f32_16x16x32_bf16(A, B, C, 0, 0, 0)
#define MFMA16(A, B, C) __builtin_amdgcn_mfma_f32_16x16x16bf16_1k(A, B, C, 0, 0, 0)

// async 16B global -> LDS. lds dest = wave-uniform base + lane*16.
#define GLOAD16(gp, lp)                                                          \
    __builtin_amdgcn_global_load_lds(                                            \
        (const __attribute__((address_space(1))) unsigned int*)(gp),             \
        (__attribute__((address_space(3))) unsigned int*)(lp), 16, 0, 0)

// ---------------- fused prep: cast x + transpose Wqkv + transpose Wproj ----------------
__global__ void prep_kernel(const float* __restrict__ x, const float* __restrict__ Wq,
                            const float* __restrict__ Wk, const float* __restrict__ Wv,
                            const float* __restrict__ Wproj,
                            unsigned short* __restrict__ xb,
                            unsigned short* __restrict__ WqkvT,
                            unsigned short* __restrict__ WprojT) {
    __shared__ unsigned short t[64][65];
    int g = blockIdx.x;
    if (g < 8192) {                       // cast x (fp32 -> bf16)
        int i = (g * 256 + (int)threadIdx.x) * 4;
        float4 v = *(const float4*)(x + i);
        ushort4 o;
        o.x = f2b(v.x); o.y = f2b(v.y); o.z = f2b(v.z); o.w = f2b(v.w);
        *(ushort4*)(xb + i) = o;
    } else if (g < 8192 + 768) {          // Wq/Wk/Wv [H][C][D] -> WqkvT [3072][1024]
        int idx = g - 8192;
        int z = idx >> 4;                 // h*3 + part
        int h = z / 3, part = z % 3;
        const float* src = (part == 0 ? Wq : (part == 1 ? Wk : Wv)) + (size_t)h * C_ * D_;
        int c0 = (idx & 15) * 64;
        for (int i = threadIdx.x; i < 4096; i += 256) {
            int r = i >> 6, d = i & 63;
            t[d][r] = f2b(src[(size_t)(c0 + r) * D_ + d]);
        }
        __syncthreads();
        unsigned short* dst = WqkvT + (size_t)(h * 192 + part * 64) * C_;
        for (int i = threadIdx.x; i < 4096; i += 256) {
            int d = i >> 6, r = i & 63;
            dst[(size_t)d * C_ + c0 + r] = t[d][r];
        }
    } else {                              // Wproj [1024][1024] -> WprojT (B^T)
        int idx = g - 8960;
        int n0 = (idx & 15) * 64, k0 = (idx >> 4) * 64;
        for (int i = threadIdx.x; i < 4096; i += 256) {
            int r = i >> 6, c = i & 63;
            t[c][r] = f2b(Wproj[(size_t)(k0 + r) * C_ + n0 + c]);
        }
        __syncthreads();
        for (int i = threadIdx.x; i < 4096; i += 256) {
            int n = i >> 6, k = i & 63;
            WprojT[(size_t)(n0 + n) * 1024 + k0 + k] = t[n][k];
        }
    }
}

// ---------------- GEMM QKV v5: 256x384 tile, 512 thr, 3-stage DMA pipeline ----------------
// DMA model: global_load_lds sustains ~16-24 B/cyc/CU -> minimize staged bytes/FLOP.
// 256x384x32 stages 40 KB for 6.29 MFLOP (157 FLOP/B vs 87 at 256x128).
// Grid = 256 blocks exactly (1/CU, no tail); n-idx = g&7 so each XCD owns one 768 KB
// B-panel (L2-resident). 8 waves as 2(M)x4(N), wave tile 128x96 (acc 192 VGPR, 2 waves/SIMD).
// 3 LDS stages (120 KB), s_waitcnt vmcnt(5) at iter top — queue never drains.
__global__ __launch_bounds__(512, 2) void gemm_qkv(const unsigned short* __restrict__ A,
                                                   const unsigned short* __restrict__ Bt,
                                                   unsigned short* __restrict__ Cout,
                                                   int M, int N, int K) {
    constexpr int ABUF = 256 * 32;       // shorts
    constexpr int BBUF = 384 * 32;
    __shared__ unsigned short lA[3 * ABUF];   // 48 KB
    __shared__ unsigned short lB[3 * BBUF];   // 72 KB
    int tid = threadIdx.x;
    int lane = tid & 63, w = tid >> 6;
    int half = lane >> 5, l32 = lane & 31;
    int wm = w >> 2, wn = w & 3;

    int g = blockIdx.x;
    int n0 = (g & 7) * 384;              // per-XCD B-panel residency
    int m0 = (g >> 3) * 256;

    // A: 1024 chunks of 16B -> 2 per thread. B: 1536 chunks -> 3 per thread.
    const unsigned short* gA[2];
    int offA[2];
    #pragma unroll
    for (int j = 0; j < 2; j++) {
        int c = j * 512 + tid;
        int row = c >> 2;
        int col8 = ((c & 3) ^ ((row >> 1) & 3)) * 8;
        gA[j] = A + (size_t)(m0 + row) * K + col8;
        offA[j] = (j * 512 + w * 64) * 16;
    }
    const unsigned short* gB[3];
    int offB[3];
    #pragma unroll
    for (int j = 0; j < 3; j++) {
        int c = j * 512 + tid;
        int row = c >> 2;
        int col8 = ((c & 3) ^ ((row >> 1) & 3)) * 8;
        gB[j] = Bt + (size_t)(n0 + row) * K + col8;
        offB[j] = (j * 512 + w * 64) * 16;
    }

    int am[4], bn[3];
    #pragma unroll
    for (int mi = 0; mi < 4; mi++) am[mi] = wm * 128 + mi * 32 + l32;
    #pragma unroll
    for (int ni = 0; ni < 3; ni++) bn[ni] = wn * 96 + ni * 32 + l32;

    v16f acc[4][3];
    #pragma unroll
    for (int mi = 0; mi < 4; mi++)
        #pragma unroll
        for (int ni = 0; ni < 3; ni++)
            #pragma unroll
            for (int r = 0; r < 16; r++) acc[mi][ni][r] = 0.f;

    int kt = K >> 5;
    // prologue: T0 -> buf0, T1 -> buf1 (5 loads per thread per tile)
    #pragma unroll
    for (int j = 0; j < 2; j++) GLOAD16(gA[j], (char*)lA + offA[j]);
    #pragma unroll
    for (int j = 0; j < 3; j++) GLOAD16(gB[j], (char*)lB + offB[j]);
    #pragma unroll
    for (int j = 0; j < 2; j++) GLOAD16(gA[j] + 32, (char*)(lA + ABUF) + offA[j]);
    #pragma unroll
    for (int j = 0; j < 3; j++) GLOAD16(gB[j] + 32, (char*)(lB + BBUF) + offB[j]);

    int cur = 0;
    for (int it = 0; it < kt; it++) {
        int nx2 = cur + 2; if (nx2 >= 3) nx2 -= 3;
        // tile[it] landed; tile[it+1]'s 5 loads may remain in flight
        __asm__ volatile("s_waitcnt vmcnt(5)" ::: "memory");
        __asm__ volatile("s_barrier" ::: "memory");
        {
            int kn = ((it + 2 < kt) ? it + 2 : kt - 1) << 5;   // clamp keeps counts fixed
            #pragma unroll
            for (int j = 0; j < 2; j++) GLOAD16(gA[j] + kn, (char*)(lA + nx2 * ABUF) + offA[j]);
            #pragma unroll
            for (int j = 0; j < 3; j++) GLOAD16(gB[j] + kn, (char*)(lB + nx2 * BBUF) + offB[j]);
        }
        const unsigned short* bufA = lA + cur * ABUF;
        const unsigned short* bufB = lB + cur * BBUF;
        #pragma unroll
        for (int step = 0; step < 2; step++) {
            int gch = step * 2 + half;
            v8s af[4], bf[3];
            #pragma unroll
            for (int mi = 0; mi < 4; mi++)
                af[mi] = *(const v8s*)&bufA[am[mi] * 32 + ((gch ^ ((am[mi] >> 1) & 3)) * 8)];
            #pragma unroll
            for (int ni = 0; ni < 3; ni++)
                bf[ni] = *(const v8s*)&bufB[bn[ni] * 32 + ((gch ^ ((bn[ni] >> 1) & 3)) * 8)];
            #pragma unroll
            for (int mi = 0; mi < 4; mi++)
                #pragma unroll
                for (int ni = 0; ni < 3; ni++)
                    acc[mi][ni] = __builtin_amdgcn_mfma_f32_32x32x16_bf16(af[mi], bf[ni], acc[mi][ni], 0, 0, 0);
        }
        cur = cur + 1; if (cur >= 3) cur -= 3;
    }
    // epilogue: C/D map col=lane&31, row=(reg&3)+8*(reg>>2)+4*(lane>>5)
    #pragma unroll
    for (int mi = 0; mi < 4; mi++) {
        #pragma unroll
        for (int ni = 0; ni < 3; ni++) {
            int col = n0 + wn * 96 + ni * 32 + l32;
            #pragma unroll
            for (int r = 0; r < 16; r++) {
                int row = m0 + wm * 128 + mi * 32 + (r & 3) + 8 * (r >> 2) + 4 * half;
                Cout[(size_t)row * N + col] = f2b(acc[mi][ni][r]);
            }
        }
    }
}

// ---------------- GEMM proj (unchanged): 128x128, 3-stage pipeline, XCD stripe ------
__global__ __launch_bounds__(256, 3) void gemm_proj(const unsigned short* __restrict__ A,
                                                    const unsigned short* __restrict__ Bt,
                                                    float* __restrict__ Cout,
                                                    const float* __restrict__ bias,
                                                    int M, int N, int K) {
    constexpr int ABUF = 128 * 32;
    constexpr int BBUF = 128 * 32;
    __shared__ unsigned short lA[3 * ABUF];
    __shared__ unsigned short lB[3 * BBUF];

    int tid = threadIdx.x;
    int lane = tid & 63, w = tid >> 6;
    int half = lane >> 5, l32 = lane & 31;
    int wm = w >> 1, wn = w & 1;

    int g = blockIdx.x;
    int nbm = M / 128;
    int stripe = nbm >> 3;
    int xcd = g & 7, s = g >> 3;
    int m0 = (xcd * stripe + (s % stripe)) * 128;
    int n0 = (s / stripe) * 128;

    const unsigned short* gA[2];
    int offA[2];
    #pragma unroll
    for (int j = 0; j < 2; j++) {
        int c = j * 256 + tid;
        int row = c >> 2;
        int col8 = ((c & 3) ^ ((row >> 1) & 3)) * 8;
        gA[j] = A + (size_t)(m0 + row) * K + col8;
        offA[j] = (j * 256 + w * 64) * 16;
    }
    const unsigned short* gB[2];
    int offB[2];
    #pragma unroll
    for (int j = 0; j < 2; j++) {
        int c = j * 256 + tid;
        int row = c >> 2;
        int col8 = ((c & 3) ^ ((row >> 1) & 3)) * 8;
        gB[j] = Bt + (size_t)(n0 + row) * K + col8;
        offB[j] = (j * 256 + w * 64) * 16;
    }

    int am[2], bn[2];
    #pragma unroll
    for (int mi = 0; mi < 2; mi++) am[mi] = wm * 64 + mi * 32 + l32;
    #pragma unroll
    for (int ni = 0; ni < 2; ni++) bn[ni] = wn * 64 + ni * 32 + l32;

    v16f acc[2][2];
    #pragma unroll
    for (int mi = 0; mi < 2; mi++)
        #pragma unroll
        for (int ni = 0; ni < 2; ni++)
            #pragma unroll
            for (int r = 0; r < 16; r++) acc[mi][ni][r] = 0.f;

    int kt = K >> 5;
    #pragma unroll
    for (int j = 0; j < 2; j++) GLOAD16(gA[j], (char*)lA + offA[j]);
    #pragma unroll
    for (int j = 0; j < 2; j++) GLOAD16(gB[j], (char*)lB + offB[j]);
    #pragma unroll
    for (int j = 0; j < 2; j++) GLOAD16(gA[j] + 32, (char*)(lA + ABUF) + offA[j]);
    #pragma unroll
    for (int j = 0; j < 2; j++) GLOAD16(gB[j] + 32, (char*)(lB + BBUF) + offB[j]);

    int cur = 0;
    for (int it = 0; it < kt; it++) {
        int nx2 = cur + 2; if (nx2 >= 3) nx2 -= 3;
        __asm__ volatile("s_waitcnt vmcnt(4)" ::: "memory");
        __asm__ volatile("s_barrier" ::: "memory");
        {
            int kn = ((it + 2 < kt) ? it + 2 : kt - 1) << 5;
            #pragma unroll
            for (int j = 0; j < 2; j++) GLOAD16(gA[j] + kn, (char*)(lA + nx2 * ABUF) + offA[j]);
            #pragma unroll
            for (int j = 0; j < 2; j++) GLOAD16(gB[j] + kn, (char*)(lB + nx2 * BBUF) + offB[j]);
        }
        const unsigned short* bufA = lA + cur * ABUF;
        const unsigned short* bufB = lB + cur * BBUF;
        #pragma unroll
        for (int step = 0; step < 2; step++) {
            int gch = step * 2 + half;
            v8s af[2], bf[2];
            #pragma unroll
            for (int mi = 0; mi < 2; mi++)
                af[mi] = *(const v8s*)&bufA[am[mi] * 32 + ((gch ^ ((am[mi] >> 1) & 3)) * 8)];
            #pragma unroll
            for (int ni = 0; ni < 2; ni++)
                bf[ni] = *(const v8s*)&bufB[bn[ni] * 32 + ((gch ^ ((bn[ni] >> 1) & 3)) * 8)];
            #pragma unroll
            for (int mi = 0; mi < 2; mi++)
                #pragma unroll
                for (int ni = 0; ni < 2; ni++)
                    acc[mi][ni] = __builtin_amdgcn_mfma_f32_32x32x16_bf16(af[mi], bf[ni], acc[mi][ni], 0, 0, 0);
        }
        cur = cur + 1; if (cur >= 3) cur -= 3;
    }
    #pragma unroll
    for (int mi = 0; mi < 2; mi++) {
        #pragma unroll
        for (int ni = 0; ni < 2; ni++) {
            int col = n0 + wn * 64 + ni * 32 + l32;
            #pragma unroll
            for (int r = 0; r < 16; r++) {
                int row = m0 + wm * 64 + mi * 32 + (r & 3) + 8 * (r >> 2) + 4 * half;
                Cout[(size_t)row * N + col] = acc[mi][ni][r] + bias[col];
            }
        }
    }
}

// ---------------- V [b,t,h,d] (inside QKV) -> Vt [b,h,d,t] ----------------
__global__ void transpose_v(const unsigned short* __restrict__ QKV, unsigned short* __restrict__ Vt) {
    int t0 = blockIdx.x * 64;
    int bh = blockIdx.y;
    int b = bh >> 4, h = bh & 15;
    __shared__ unsigned short t[64][65];
    for (int i = threadIdx.x; i < 4096; i += 256) {
        int r = i >> 6, d = i & 63;
        t[d][r] = QKV[(size_t)(b * T_ + t0 + r) * QKVLD + h * 192 + 128 + d];
    }
    __syncthreads();
    for (int i = threadIdx.x; i < 4096; i += 256) {
        int d = i >> 6, r = i & 63;
        Vt[((size_t)bh * 64 + d) * T_ + t0 + r] = t[d][r];
    }
}

// ---------------- Flash attention v5 (unchanged): S-transposed, register-resident P ------
__global__ __launch_bounds__(256) void attn_kernel(const unsigned short* __restrict__ QKV,
                                                   const unsigned short* __restrict__ Vt,
                                                   unsigned short* __restrict__ Ob) {
    int bh = blockIdx.x;
    int qt = 7 - blockIdx.y;
    int b = bh >> 4, h = bh & 15;
    int tid = threadIdx.x, lane = tid & 63, w = tid >> 6;
    int quad = lane >> 4, l16 = lane & 15;
    int qg0 = qt * 128 + w * 32;

    __shared__ unsigned short lK[2][2][64][32];
    __shared__ unsigned short lV[2][64][32];

    v8s aq[2][2];
    #pragma unroll
    for (int st = 0; st < 2; st++) {
        const unsigned short* qp = QKV + (size_t)(b * T_ + qg0 + st * 16 + l16) * QKVLD + h * 192;
        aq[st][0] = *(const v8s*)(qp + quad * 8);
        aq[st][1] = *(const v8s*)(qp + 32 + quad * 8);
    }

    const unsigned short* gK[2];
    const unsigned short* gV[2];
    int ldsOff[2];
    #pragma unroll
    for (int j = 0; j < 2; j++) {
        int c = j * 256 + tid;
        int halfp = c >> 8, row = (c >> 2) & 63;
        int col8 = ((c & 3) ^ ((row >> 1) & 3)) * 8;
        gK[j] = QKV + (size_t)(b * T_ + row) * QKVLD + h * 192 + 64 + halfp * 32 + col8;
        gV[j] = Vt + ((size_t)bh * 64 + row) * T_ + halfp * 32 + col8;
        ldsOff[j] = (j * 256 + w * 64) * 16;
    }
    int rcol = (quad ^ ((l16 >> 1) & 3)) * 8;

    v4f accO[2][4];
    float lsum[2] = {0.f, 0.f};
    #pragma unroll
    for (int st = 0; st < 2; st++)
        #pragma unroll
        for (int i = 0; i < 4; i++) accO[st][i] = (v4f){0.f, 0.f, 0.f, 0.f};

    int ntiles = 2 * qt + 2;
    const float SC = 0.1803368801f;  // 0.125 * log2(e)

    #pragma unroll
    for (int j = 0; j < 2; j++)
        GLOAD16(gK[j], (char*)&lK[0][0][0][0] + ldsOff[j]);

    for (int it = 0; it < ntiles; it++) {
        int cur = it & 1, nxt = cur ^ 1;
        int s0 = it * 64;
        __asm__ volatile("s_waitcnt vmcnt(0)" ::: "memory");
        __asm__ volatile("s_barrier" ::: "memory");
        #pragma unroll
        for (int j = 0; j < 2; j++)
            GLOAD16(gV[j] + s0, (char*)&lV[0][0][0] + ldsOff[j]);
        __asm__ volatile("" ::: "memory");
        {
            int itn = (it + 1 < ntiles) ? it + 1 : it;
            size_t koff = (size_t)itn * 64 * QKVLD;
            #pragma unroll
            for (int j = 0; j < 2; j++)
                GLOAD16(gK[j] + koff, (char*)&lK[nxt][0][0][0] + ldsOff[j]);
        }
        bool act0 = (qg0 + 15 >= s0);
        bool act1 = (qg0 + 31 >= s0);
        v4s pP[2][4];
        if (act1) {
            v4f sf[2][4];
            #pragma unroll
            for (int nt = 0; nt < 4; nt++) {
                v8s bk0 = *(const v8s*)&lK[cur][0][nt * 16 + l16][rcol];
                v8s bk1 = *(const v8s*)&lK[cur][1][nt * 16 + l16][rcol];
                v4f a1 = (v4f){0.f, 0.f, 0.f, 0.f};
                a1 = MFMA32(bk0, aq[1][0], a1);
                a1 = MFMA32(bk1, aq[1][1], a1);
                sf[1][nt] = a1;
                if (act0) {
                    v4f a0 = (v4f){0.f, 0.f, 0.f, 0.f};
                    a0 = MFMA32(bk0, aq[0][0], a0);
                    a0 = MFMA32(bk1, aq[0][1], a0);
                    sf[0][nt] = a0;
                }
            }
            bool diag = (it >= ntiles - 2);
            #pragma unroll
            for (int st = 0; st < 2; st++) {
                if (st == 0 && !act0) continue;
                int qg = qg0 + st * 16 + l16;
                #pragma unroll
                for (int nt = 0; nt < 4; nt++) {
                    float p[4];
                    #pragma unroll
                    for (int r = 0; r < 4; r++) {
                        if (diag) {
                            int sg = s0 + nt * 16 + quad * 4 + r;
                            p[r] = (sg > qg) ? 0.f : fexp2(sf[st][nt][r] * SC);
                        } else {
                            p[r] = fexp2(sf[st][nt][r] * SC);
                        }
                        lsum[st] += p[r];
                    }
                    pP[st][nt] = pack4(p[0], p[1], p[2], p[3]);
                }
            }
        }
        __asm__ volatile("s_waitcnt vmcnt(2)" ::: "memory");
        __asm__ volatile("s_barrier" ::: "memory");
        if (act1) {
            #pragma unroll
            for (int kb = 0; kb < 4; kb++) {
                int sc_ = kb >> 1;
                int ccg = (kb & 1) * 2 + (quad >> 1);
                #pragma unroll
                for (int dt = 0; dt < 4; dt++) {
                    int d = dt * 16 + l16;
                    int ccp = ccg ^ ((l16 >> 1) & 3);
                    v4s bv = *(const v4s*)&lV[sc_][d][ccp * 8 + (quad & 1) * 4];
                    accO[1][dt] = MFMA16(pP[1][kb], bv, accO[1][dt]);
                    if (act0) accO[0][dt] = MFMA16(pP[0][kb], bv, accO[0][dt]);
                }
            }
        }
    }
    #pragma unroll
    for (int st = 0; st < 2; st++) {
        float ls = lsum[st];
        ls += __shfl_xor(ls, 16, 64);
        ls += __shfl_xor(ls, 32, 64);
        #pragma unroll
        for (int r = 0; r < 4; r++) {
            float lq = __shfl(ls, quad * 4 + r, 64);
            float inv = 1.0f / lq;
            int q = qg0 + st * 16 + quad * 4 + r;
            #pragma unroll
            for (int dt = 0; dt < 4; dt++) {
                int d = dt * 16 + l16;
                Ob[(size_t)(b * T_ + q) * (H_ * D_) + h * 64 + d] = f2b(accO[st][dt][r] * inv);
            }
        }
    }
}

extern "C" void kernel_launch(void* const* d_in, const int* in_sizes, int n_in,
                              void* d_out, int out_size, void* d_ws, size_t ws_size,
                              hipStream_t stream) {
    const float* x     = (const float*)d_in[0];
    const float* Wq    = (const float*)d_in[1];
    const float* Wk    = (const float*)d_in[2];
    const float* Wv    = (const float*)d_in[3];
    const float* Wproj = (const float*)d_in[4];
    const float* bproj = (const float*)d_in[5];
    float* out = (float*)d_out;

    char* ws = (char*)d_ws;
    unsigned short* xb     = (unsigned short*)ws;                          // 16 MB  [8192][1024]
    unsigned short* WqkvT  = (unsigned short*)(ws + 16777216);             // 6 MB   [3072][1024]
    unsigned short* WprojT = (unsigned short*)(ws + 23068672);             // 2 MB   [1024][1024]
    unsigned short* QKV    = (unsigned short*)(ws + 25165824);             // 48 MB  [8192][3072]
    unsigned short* Vt     = (unsigned short*)(ws + 75497472);             // 16 MB  [B,H,D,T]
    unsigned short* Ob     = (unsigned short*)(ws + 92274688);             // 16 MB  [8192][1024]

    prep_kernel<<<dim3(9216), dim3(256), 0, stream>>>(x, Wq, Wk, Wv, Wproj, xb, WqkvT, WprojT);
    gemm_qkv<<<dim3(256), dim3(512), 0, stream>>>(xb, WqkvT, QKV, 8192, 3072, 1024);
    transpose_v<<<dim3(16, 128), dim3(256), 0, stream>>>(QKV, Vt);
    attn_kernel<<<dim3(128, 8), dim3(256), 0, stream>>>(QKV, Vt, Ob);
    gemm_proj<<<dim3(512), dim3(256), 0, stream>>>(Ob, WprojT, out, bproj, 8192, 1024, 1024);
}

// Round 11
// 240.690 us; speedup vs baseline: 1.0047x; 1.0047x over previous
//
#include <hip/hip_runtime.h>
#include <hip/hip_bf16.h>

#define B_ 8
#define T_ 1024
#define C_ 1024
#define H_ 16
#define D_ 64
#define QKVLD 3072  // H_*3*D_  (layout: [Q(1024) | K(1024) | V(1024)], col = part*1024 + h*64 + d)

typedef short v4s __attribute__((ext_vector_type(4)));
typedef short v8s __attribute__((ext_vector_type(8)));
typedef float v4f __attribute__((ext_vector_type(4)));
typedef float v16f __attribute__((ext_vector_type(16)));

__device__ __forceinline__ unsigned short f2b(float f) {
    unsigned int u = __builtin_bit_cast(unsigned int, f);
    unsigned int lsb = (u >> 16) & 1u;
    u += 0x7fffu + lsb;
    return (unsigned short)(u >> 16);
}

__device__ __forceinline__ float fexp2(float x) {
    return __expf(x * 0.69314718056f);   // compiler folds to v_exp_f32
}

// pack 4 fp32 -> 4 bf16 (round-half-up; inputs are P in [0,1], no NaN/neg)
__device__ __forceinline__ v4s pack4(float p0, float p1, float p2, float p3) {
    unsigned int a = (__builtin_bit_cast(unsigned int, p0) + 0x8000u) >> 16;
    unsigned int b = (__builtin_bit_cast(unsigned int, p1) + 0x8000u) & 0xFFFF0000u;
    unsigned int c = (__builtin_bit_cast(unsigned int, p2) + 0x8000u) >> 16;
    unsigned int d = (__builtin_bit_cast(unsigned int, p3) + 0x8000u) & 0xFFFF0000u;
    union { unsigned int u[2]; v4s v; } t;
    t.u[0] = a | b; t.u[1] = c | d;
    return t.v;
}

#define MFMA32(A, B, C) __builtin_amdgcn_mfma_f32_16x16x32_bf16(A, B, C, 0, 0, 0)
#define MFMA16(A, B, C) __builtin_amdgcn_mfma_f32_16x16x16bf16_1k(A, B, C, 0, 0, 0)

// async 16B global -> LDS. lds dest = wave-uniform base + lane*16.
#define GLOAD16(gp, lp)                                                          \
    __builtin_amdgcn_global_load_lds(                                            \
        (const __attribute__((address_space(1))) unsigned int*)(gp),             \
        (__attribute__((address_space(3))) unsigned int*)(lp), 16, 0, 0)

// ---------------- fused prep: cast x + transpose Wqkv + transpose Wproj ----------------
__global__ void prep_kernel(const float* __restrict__ x, const float* __restrict__ Wq,
                            const float* __restrict__ Wk, const float* __restrict__ Wv,
                            const float* __restrict__ Wproj,
                            unsigned short* __restrict__ xb,
                            unsigned short* __restrict__ WqkvT,
                            unsigned short* __restrict__ WprojT) {
    __shared__ unsigned short t[64][65];
    int g = blockIdx.x;
    if (g < 8192) {                       // cast x (fp32 -> bf16)
        int i = (g * 256 + (int)threadIdx.x) * 4;
        float4 v = *(const float4*)(x + i);
        ushort4 o;
        o.x = f2b(v.x); o.y = f2b(v.y); o.z = f2b(v.z); o.w = f2b(v.w);
        *(ushort4*)(xb + i) = o;
    } else if (g < 8192 + 768) {          // Wq/Wk/Wv [H][C][D] -> WqkvT rows part*1024+h*64+d
        int idx = g - 8192;
        int z = idx >> 4;                 // h*3 + part
        int h = z / 3, part = z % 3;
        const float* src = (part == 0 ? Wq : (part == 1 ? Wk : Wv)) + (size_t)h * C_ * D_;
        int c0 = (idx & 15) * 64;
        for (int i = threadIdx.x; i < 4096; i += 256) {
            int r = i >> 6, d = i & 63;
            t[d][r] = f2b(src[(size_t)(c0 + r) * D_ + d]);
        }
        __syncthreads();
        unsigned short* dst = WqkvT + (size_t)(part * 1024 + h * 64) * C_;
        for (int i = threadIdx.x; i < 4096; i += 256) {
            int d = i >> 6, r = i & 63;
            dst[(size_t)d * C_ + c0 + r] = t[d][r];
        }
    } else {                              // Wproj [1024][1024] -> WprojT (B^T)
        int idx = g - 8960;
        int n0 = (idx & 15) * 64, k0 = (idx >> 4) * 64;
        for (int i = threadIdx.x; i < 4096; i += 256) {
            int r = i >> 6, c = i & 63;
            t[c][r] = f2b(Wproj[(size_t)(k0 + r) * C_ + n0 + c]);
        }
        __syncthreads();
        for (int i = threadIdx.x; i < 4096; i += 256) {
            int n = i >> 6, k = i & 63;
            WprojT[(size_t)(n0 + n) * 1024 + k0 + k] = t[n][k];
        }
    }
}

// ---------------- GEMM QKV (R7-exact loop): 256x128, 32x32x16 MFMA, 2-stage dbuf ---------
// V n-blocks (n0 >= 2048) write their output TRANSPOSED to Vt[b,h,d,t] via an LDS staging
// pass in the epilogue — replaces the separate transpose_v kernel.
__global__ __launch_bounds__(256, 2) void gemm_qkv(const unsigned short* __restrict__ A,
                                                   const unsigned short* __restrict__ Bt,
                                                   unsigned short* __restrict__ Cout,
                                                   unsigned short* __restrict__ Vt,
                                                   int M, int N, int K) {
    constexpr int ABUF = 256 * 32;   // shorts
    constexpr int BBUF = 128 * 32;
    __shared__ unsigned short smem[2 * ABUF + 2 * BBUF];   // 48 KB
    unsigned short* lA0 = smem;
    unsigned short* lB0 = smem + 2 * ABUF;

    int tid = threadIdx.x;
    int m0 = blockIdx.y * 256, n0 = blockIdx.x * 128;
    int lane = tid & 63, w = tid >> 6;
    int half = lane >> 5, l32 = lane & 31;
    int wm = w >> 1, wn = w & 1;

    const unsigned short* gA[4];
    int offA[4];
    #pragma unroll
    for (int j = 0; j < 4; j++) {
        int c = j * 256 + tid;
        int row = c >> 2;
        int col8 = ((c & 3) ^ ((row >> 1) & 3)) * 8;
        gA[j] = A + (size_t)(m0 + row) * K + col8;
        offA[j] = (j * 256 + w * 64) * 16;
    }
    const unsigned short* gB[2];
    int offB[2];
    #pragma unroll
    for (int j = 0; j < 2; j++) {
        int c = j * 256 + tid;
        int row = c >> 2;
        int col8 = ((c & 3) ^ ((row >> 1) & 3)) * 8;
        gB[j] = Bt + (size_t)(n0 + row) * K + col8;
        offB[j] = (j * 256 + w * 64) * 16;
    }

    int am[4], bn[2];
    #pragma unroll
    for (int mi = 0; mi < 4; mi++) am[mi] = wm * 128 + mi * 32 + l32;
    #pragma unroll
    for (int ni = 0; ni < 2; ni++) bn[ni] = wn * 64 + ni * 32 + l32;

    v16f acc[4][2];
    #pragma unroll
    for (int mi = 0; mi < 4; mi++)
        #pragma unroll
        for (int ni = 0; ni < 2; ni++)
            #pragma unroll
            for (int r = 0; r < 16; r++) acc[mi][ni][r] = 0.f;

    int ktiles = K >> 5;
    #pragma unroll
    for (int j = 0; j < 4; j++) GLOAD16(gA[j], (char*)lA0 + offA[j]);
    #pragma unroll
    for (int j = 0; j < 2; j++) GLOAD16(gB[j], (char*)lB0 + offB[j]);

    for (int it = 0; it < ktiles; it++) {
        int cur = it & 1, nxt = cur ^ 1;
        __asm__ volatile("s_waitcnt vmcnt(0)" ::: "memory");
        __asm__ volatile("s_barrier" ::: "memory");
        {
            int kn = (it + 1 < ktiles) ? (it + 1) * 32 : it * 32;
            #pragma unroll
            for (int j = 0; j < 4; j++) GLOAD16(gA[j] + kn, (char*)(lA0 + nxt * ABUF) + offA[j]);
            #pragma unroll
            for (int j = 0; j < 2; j++) GLOAD16(gB[j] + kn, (char*)(lB0 + nxt * BBUF) + offB[j]);
        }
        const unsigned short* bufA = lA0 + cur * ABUF;
        const unsigned short* bufB = lB0 + cur * BBUF;
        #pragma unroll
        for (int step = 0; step < 2; step++) {
            int g = step * 2 + half;
            v8s af[4], bf[2];
            #pragma unroll
            for (int mi = 0; mi < 4; mi++)
                af[mi] = *(const v8s*)&bufA[am[mi] * 32 + ((g ^ ((am[mi] >> 1) & 3)) * 8)];
            #pragma unroll
            for (int ni = 0; ni < 2; ni++)
                bf[ni] = *(const v8s*)&bufB[bn[ni] * 32 + ((g ^ ((bn[ni] >> 1) & 3)) * 8)];
            #pragma unroll
            for (int mi = 0; mi < 4; mi++)
                #pragma unroll
                for (int ni = 0; ni < 2; ni++)
                    acc[mi][ni] = __builtin_amdgcn_mfma_f32_32x32x16_bf16(af[mi], bf[ni], acc[mi][ni], 0, 0, 0);
        }
    }
    if (n0 < 2048) {
        // Q/K blocks: plain write. C/D map col=lane&31, row=(reg&3)+8*(reg>>2)+4*(lane>>5)
        #pragma unroll
        for (int mi = 0; mi < 4; mi++) {
            #pragma unroll
            for (int ni = 0; ni < 2; ni++) {
                int col = n0 + wn * 64 + ni * 32 + l32;
                #pragma unroll
                for (int r = 0; r < 16; r++) {
                    int row = m0 + wm * 128 + mi * 32 + (r & 3) + 8 * (r >> 2) + 4 * half;
                    Cout[(size_t)row * N + col] = f2b(acc[mi][ni][r]);
                }
            }
        }
    } else {
        // V blocks: transpose 256(t) x 128(col) tile via LDS, write Vt[b,h,d,t] coalesced.
        unsigned short* sT = smem;          // [64][258] staging, 33 KB
        int bB = m0 >> 10;                  // batch (256-row tile lies in one batch)
        int t0 = m0 & 1023;
        #pragma unroll
        for (int p = 0; p < 2; p++) {
            __syncthreads();                // prior smem users (loop / prev pass) done
            if (wn == p) {
                #pragma unroll
                for (int mi = 0; mi < 4; mi++)
                    #pragma unroll
                    for (int ni = 0; ni < 2; ni++) {
                        int cl = ni * 32 + l32;
                        #pragma unroll
                        for (int r = 0; r < 16; r++) {
                            int rowl = wm * 128 + mi * 32 + (r & 3) + 8 * (r >> 2) + 4 * half;
                            sT[cl * 258 + rowl] = f2b(acc[mi][ni][r]);
                        }
                    }
            }
            __syncthreads();
            #pragma unroll
            for (int j = 0; j < 8; j++) {
                int c = j * 256 + tid;
                int rw = c >> 5, ch = c & 31;
                int vcol = (n0 - 2048) + p * 64 + rw;    // = h*64 + d
                int hh = vcol >> 6, dd = vcol & 63;
                *(v8s*)&Vt[(((size_t)bB * 16 + hh) * 64 + dd) * T_ + t0 + ch * 8] =
                    *(const v8s*)&sT[rw * 258 + ch * 8];
            }
        }
    }
}

// ---------------- GEMM proj (unchanged): 128x128, 3-stage pipeline, XCD stripe ------
__global__ __launch_bounds__(256, 3) void gemm_proj(const unsigned short* __restrict__ A,
                                                    const unsigned short* __restrict__ Bt,
                                                    float* __restrict__ Cout,
                                                    const float* __restrict__ bias,
                                                    int M, int N, int K) {
    constexpr int ABUF = 128 * 32;
    constexpr int BBUF = 128 * 32;
    __shared__ unsigned short lA[3 * ABUF];
    __shared__ unsigned short lB[3 * BBUF];

    int tid = threadIdx.x;
    int lane = tid & 63, w = tid >> 6;
    int half = lane >> 5, l32 = lane & 31;
    int wm = w >> 1, wn = w & 1;

    int g = blockIdx.x;
    int nbm = M / 128;
    int stripe = nbm >> 3;
    int xcd = g & 7, s = g >> 3;
    int m0 = (xcd * stripe + (s % stripe)) * 128;
    int n0 = (s / stripe) * 128;

    const unsigned short* gA[2];
    int offA[2];
    #pragma unroll
    for (int j = 0; j < 2; j++) {
        int c = j * 256 + tid;
        int row = c >> 2;
        int col8 = ((c & 3) ^ ((row >> 1) & 3)) * 8;
        gA[j] = A + (size_t)(m0 + row) * K + col8;
        offA[j] = (j * 256 + w * 64) * 16;
    }
    const unsigned short* gB[2];
    int offB[2];
    #pragma unroll
    for (int j = 0; j < 2; j++) {
        int c = j * 256 + tid;
        int row = c >> 2;
        int col8 = ((c & 3) ^ ((row >> 1) & 3)) * 8;
        gB[j] = Bt + (size_t)(n0 + row) * K + col8;
        offB[j] = (j * 256 + w * 64) * 16;
    }

    int am[2], bn[2];
    #pragma unroll
    for (int mi = 0; mi < 2; mi++) am[mi] = wm * 64 + mi * 32 + l32;
    #pragma unroll
    for (int ni = 0; ni < 2; ni++) bn[ni] = wn * 64 + ni * 32 + l32;

    v16f acc[2][2];
    #pragma unroll
    for (int mi = 0; mi < 2; mi++)
        #pragma unroll
        for (int ni = 0; ni < 2; ni++)
            #pragma unroll
            for (int r = 0; r < 16; r++) acc[mi][ni][r] = 0.f;

    int kt = K >> 5;
    #pragma unroll
    for (int j = 0; j < 2; j++) GLOAD16(gA[j], (char*)lA + offA[j]);
    #pragma unroll
    for (int j = 0; j < 2; j++) GLOAD16(gB[j], (char*)lB + offB[j]);
    #pragma unroll
    for (int j = 0; j < 2; j++) GLOAD16(gA[j] + 32, (char*)(lA + ABUF) + offA[j]);
    #pragma unroll
    for (int j = 0; j < 2; j++) GLOAD16(gB[j] + 32, (char*)(lB + BBUF) + offB[j]);

    int cur = 0;
    for (int it = 0; it < kt; it++) {
        int nx2 = cur + 2; if (nx2 >= 3) nx2 -= 3;
        __asm__ volatile("s_waitcnt vmcnt(4)" ::: "memory");
        __asm__ volatile("s_barrier" ::: "memory");
        {
            int kn = ((it + 2 < kt) ? it + 2 : kt - 1) << 5;
            #pragma unroll
            for (int j = 0; j < 2; j++) GLOAD16(gA[j] + kn, (char*)(lA + nx2 * ABUF) + offA[j]);
            #pragma unroll
            for (int j = 0; j < 2; j++) GLOAD16(gB[j] + kn, (char*)(lB + nx2 * BBUF) + offB[j]);
        }
        const unsigned short* bufA = lA + cur * ABUF;
        const unsigned short* bufB = lB + cur * BBUF;
        #pragma unroll
        for (int step = 0; step < 2; step++) {
            int gch = step * 2 + half;
            v8s af[2], bf[2];
            #pragma unroll
            for (int mi = 0; mi < 2; mi++)
                af[mi] = *(const v8s*)&bufA[am[mi] * 32 + ((gch ^ ((am[mi] >> 1) & 3)) * 8)];
            #pragma unroll
            for (int ni = 0; ni < 2; ni++)
                bf[ni] = *(const v8s*)&bufB[bn[ni] * 32 + ((gch ^ ((bn[ni] >> 1) & 3)) * 8)];
            #pragma unroll
            for (int mi = 0; mi < 2; mi++)
                #pragma unroll
                for (int ni = 0; ni < 2; ni++)
                    acc[mi][ni] = __builtin_amdgcn_mfma_f32_32x32x16_bf16(af[mi], bf[ni], acc[mi][ni], 0, 0, 0);
        }
        cur = cur + 1; if (cur >= 3) cur -= 3;
    }
    #pragma unroll
    for (int mi = 0; mi < 2; mi++) {
        #pragma unroll
        for (int ni = 0; ni < 2; ni++) {
            int col = n0 + wn * 64 + ni * 32 + l32;
            #pragma unroll
            for (int r = 0; r < 16; r++) {
                int row = m0 + wm * 64 + mi * 32 + (r & 3) + 8 * (r >> 2) + 4 * half;
                Cout[(size_t)row * N + col] = acc[mi][ni][r] + bias[col];
            }
        }
    }
}

// ---------------- Flash attention v5 (layout-rebased): S-transposed, register-resident P -
__global__ __launch_bounds__(256) void attn_kernel(const unsigned short* __restrict__ QKV,
                                                   const unsigned short* __restrict__ Vt,
                                                   unsigned short* __restrict__ Ob) {
    int bh = blockIdx.x;
    int qt = 7 - blockIdx.y;
    int b = bh >> 4, h = bh & 15;
    int tid = threadIdx.x, lane = tid & 63, w = tid >> 6;
    int quad = lane >> 4, l16 = lane & 15;
    int qg0 = qt * 128 + w * 32;

    __shared__ unsigned short lK[2][2][64][32];
    __shared__ unsigned short lV[2][64][32];

    v8s aq[2][2];
    #pragma unroll
    for (int st = 0; st < 2; st++) {
        const unsigned short* qp = QKV + (size_t)(b * T_ + qg0 + st * 16 + l16) * QKVLD + h * 64;
        aq[st][0] = *(const v8s*)(qp + quad * 8);
        aq[st][1] = *(const v8s*)(qp + 32 + quad * 8);
    }

    const unsigned short* gK[2];
    const unsigned short* gV[2];
    int ldsOff[2];
    #pragma unroll
    for (int j = 0; j < 2; j++) {
        int c = j * 256 + tid;
        int halfp = c >> 8, row = (c >> 2) & 63;
        int col8 = ((c & 3) ^ ((row >> 1) & 3)) * 8;
        gK[j] = QKV + (size_t)(b * T_ + row) * QKVLD + 1024 + h * 64 + halfp * 32 + col8;
        gV[j] = Vt + ((size_t)bh * 64 + row) * T_ + halfp * 32 + col8;
        ldsOff[j] = (j * 256 + w * 64) * 16;
    }
    int rcol = (quad ^ ((l16 >> 1) & 3)) * 8;

    v4f accO[2][4];
    float lsum[2] = {0.f, 0.f};
    #pragma unroll
    for (int st = 0; st < 2; st++)
        #pragma unroll
        for (int i = 0; i < 4; i++) accO[st][i] = (v4f){0.f, 0.f, 0.f, 0.f};

    int ntiles = 2 * qt + 2;
    const float SC = 0.1803368801f;  // 0.125 * log2(e)

    #pragma unroll
    for (int j = 0; j < 2; j++)
        GLOAD16(gK[j], (char*)&lK[0][0][0][0] + ldsOff[j]);

    for (int it = 0; it < ntiles; it++) {
        int cur = it & 1, nxt = cur ^ 1;
        int s0 = it * 64;
        __asm__ volatile("s_waitcnt vmcnt(0)" ::: "memory");
        __asm__ volatile("s_barrier" ::: "memory");
        #pragma unroll
        for (int j = 0; j < 2; j++)
            GLOAD16(gV[j] + s0, (char*)&lV[0][0][0] + ldsOff[j]);
        __asm__ volatile("" ::: "memory");
        {
            int itn = (it + 1 < ntiles) ? it + 1 : it;
            size_t koff = (size_t)itn * 64 * QKVLD;
            #pragma unroll
            for (int j = 0; j < 2; j++)
                GLOAD16(gK[j] + koff, (char*)&lK[nxt][0][0][0] + ldsOff[j]);
        }
        bool act0 = (qg0 + 15 >= s0);
        bool act1 = (qg0 + 31 >= s0);
        v4s pP[2][4];
        if (act1) {
            v4f sf[2][4];
            #pragma unroll
            for (int nt = 0; nt < 4; nt++) {
                v8s bk0 = *(const v8s*)&lK[cur][0][nt * 16 + l16][rcol];
                v8s bk1 = *(const v8s*)&lK[cur][1][nt * 16 + l16][rcol];
                v4f a1 = (v4f){0.f, 0.f, 0.f, 0.f};
                a1 = MFMA32(bk0, aq[1][0], a1);
                a1 = MFMA32(bk1, aq[1][1], a1);
                sf[1][nt] = a1;
                if (act0) {
                    v4f a0 = (v4f){0.f, 0.f, 0.f, 0.f};
                    a0 = MFMA32(bk0, aq[0][0], a0);
                    a0 = MFMA32(bk1, aq[0][1], a0);
                    sf[0][nt] = a0;
                }
            }
            bool diag = (it >= ntiles - 2);
            #pragma unroll
            for (int st = 0; st < 2; st++) {
                if (st == 0 && !act0) continue;
                int qg = qg0 + st * 16 + l16;
                #pragma unroll
                for (int nt = 0; nt < 4; nt++) {
                    float p[4];
                    #pragma unroll
                    for (int r = 0; r < 4; r++) {
                        if (diag) {
                            int sg = s0 + nt * 16 + quad * 4 + r;
                            p[r] = (sg > qg) ? 0.f : fexp2(sf[st][nt][r] * SC);
                        } else {
                            p[r] = fexp2(sf[st][nt][r] * SC);
                        }
                        lsum[st] += p[r];
                    }
                    pP[st][nt] = pack4(p[0], p[1], p[2], p[3]);
                }
            }
        }
        __asm__ volatile("s_waitcnt vmcnt(2)" ::: "memory");
        __asm__ volatile("s_barrier" ::: "memory");
        if (act1) {
            #pragma unroll
            for (int kb = 0; kb < 4; kb++) {
                int sc_ = kb >> 1;
                int ccg = (kb & 1) * 2 + (quad >> 1);
                #pragma unroll
                for (int dt = 0; dt < 4; dt++) {
                    int d = dt * 16 + l16;
                    int ccp = ccg ^ ((l16 >> 1) & 3);
                    v4s bv = *(const v4s*)&lV[sc_][d][ccp * 8 + (quad & 1) * 4];
                    accO[1][dt] = MFMA16(pP[1][kb], bv, accO[1][dt]);
                    if (act0) accO[0][dt] = MFMA16(pP[0][kb], bv, accO[0][dt]);
                }
            }
        }
    }
    #pragma unroll
    for (int st = 0; st < 2; st++) {
        float ls = lsum[st];
        ls += __shfl_xor(ls, 16, 64);
        ls += __shfl_xor(ls, 32, 64);
        #pragma unroll
        for (int r = 0; r < 4; r++) {
            float lq = __shfl(ls, quad * 4 + r, 64);
            float inv = 1.0f / lq;
            int q = qg0 + st * 16 + quad * 4 + r;
            #pragma unroll
            for (int dt = 0; dt < 4; dt++) {
                int d = dt * 16 + l16;
                Ob[(size_t)(b * T_ + q) * (H_ * D_) + h * 64 + d] = f2b(accO[st][dt][r] * inv);
            }
        }
    }
}

extern "C" void kernel_launch(void* const* d_in, const int* in_sizes, int n_in,
                              void* d_out, int out_size, void* d_ws, size_t ws_size,
                              hipStream_t stream) {
    const float* x     = (const float*)d_in[0];
    const float* Wq    = (const float*)d_in[1];
    const float* Wk    = (const float*)d_in[2];
    const float* Wv    = (const float*)d_in[3];
    const float* Wproj = (const float*)d_in[4];
    const float* bproj = (const float*)d_in[5];
    float* out = (float*)d_out;

    char* ws = (char*)d_ws;
    unsigned short* xb     = (unsigned short*)ws;                          // 16 MB  [8192][1024]
    unsigned short* WqkvT  = (unsigned short*)(ws + 16777216);             // 6 MB   [3072][1024]
    unsigned short* WprojT = (unsigned short*)(ws + 23068672);             // 2 MB   [1024][1024]
    unsigned short* QKV    = (unsigned short*)(ws + 25165824);             // 48 MB  [8192][3072] (Q|K|V sections)
    unsigned short* Vt     = (unsigned short*)(ws + 75497472);             // 16 MB  [B,H,D,T]
    unsigned short* Ob     = (unsigned short*)(ws + 92274688);             // 16 MB  [8192][1024]

    prep_kernel<<<dim3(9216), dim3(256), 0, stream>>>(x, Wq, Wk, Wv, Wproj, xb, WqkvT, WprojT);
    gemm_qkv<<<dim3(24, 32), dim3(256), 0, stream>>>(xb, WqkvT, QKV, Vt, 8192, 3072, 1024);
    attn_kernel<<<dim3(128, 8), dim3(256), 0, stream>>>(QKV, Vt, Ob);
    gemm_proj<<<dim3(512), dim3(256), 0, stream>>>(Ob, WprojT, out, bproj, 8192, 1024, 1024);
}

// Round 12
// 236.713 us; speedup vs baseline: 1.0216x; 1.0168x over previous
//
#include <hip/hip_runtime.h>
#include <hip/hip_bf16.h>

#define B_ 8
#define T_ 1024
#define C_ 1024
#define H_ 16
#define D_ 64
#define QKVLD 3072  // [Q(1024) | K(1024) | V(unused)] ; col = part*1024 + h*64 + d

typedef short v4s __attribute__((ext_vector_type(4)));
typedef short v8s __attribute__((ext_vector_type(8)));
typedef float v4f __attribute__((ext_vector_type(4)));
typedef float v16f __attribute__((ext_vector_type(16)));

__device__ __forceinline__ unsigned short f2b(float f) {
    unsigned int u = __builtin_bit_cast(unsigned int, f);
    unsigned int lsb = (u >> 16) & 1u;
    u += 0x7fffu + lsb;
    return (unsigned short)(u >> 16);
}

__device__ __forceinline__ float fexp2(float x) {
    return __expf(x * 0.69314718056f);
}

__device__ __forceinline__ v4s pack4(float p0, float p1, float p2, float p3) {
    unsigned int a = (__builtin_bit_cast(unsigned int, p0) + 0x8000u) >> 16;
    unsigned int b = (__builtin_bit_cast(unsigned int, p1) + 0x8000u) & 0xFFFF0000u;
    unsigned int c = (__builtin_bit_cast(unsigned int, p2) + 0x8000u) >> 16;
    unsigned int d = (__builtin_bit_cast(unsigned int, p3) + 0x8000u) & 0xFFFF0000u;
    union { unsigned int u[2]; v4s v; } t;
    t.u[0] = a | b; t.u[1] = c | d;
    return t.v;
}

#define MFMA32(A, B, C) __builtin_amdgcn_mfma_f32_16x16x32_bf16(A, B, C, 0, 0, 0)
#define MFMA16(A, B, C) __builtin_amdgcn_mfma_f32_16x16x16bf16_1k(A, B, C, 0, 0, 0)

#define GLOAD16(gp, lp)                                                          \
    __builtin_amdgcn_global_load_lds(                                            \
        (const __attribute__((address_space(1))) unsigned int*)(gp),             \
        (__attribute__((address_space(3))) unsigned int*)(lp), 16, 0, 0)

// ---------------- fused prep: cast x + transpose Wqkv + transpose Wproj ----------------
__global__ void prep_kernel(const float* __restrict__ x, const float* __restrict__ Wq,
                            const float* __restrict__ Wk, const float* __restrict__ Wv,
                            const float* __restrict__ Wproj,
                            unsigned short* __restrict__ xb,
                            unsigned short* __restrict__ WqkvT,
                            unsigned short* __restrict__ WprojT) {
    __shared__ unsigned short t[64][65];
    int g = blockIdx.x;
    if (g < 8192) {
        int i = (g * 256 + (int)threadIdx.x) * 4;
        float4 v = *(const float4*)(x + i);
        ushort4 o;
        o.x = f2b(v.x); o.y = f2b(v.y); o.z = f2b(v.z); o.w = f2b(v.w);
        *(ushort4*)(xb + i) = o;
    } else if (g < 8192 + 768) {
        int idx = g - 8192;
        int z = idx >> 4;
        int h = z / 3, part = z % 3;
        const float* src = (part == 0 ? Wq : (part == 1 ? Wk : Wv)) + (size_t)h * C_ * D_;
        int c0 = (idx & 15) * 64;
        for (int i = threadIdx.x; i < 4096; i += 256) {
            int r = i >> 6, d = i & 63;
            t[d][r] = f2b(src[(size_t)(c0 + r) * D_ + d]);
        }
        __syncthreads();
        unsigned short* dst = WqkvT + (size_t)(part * 1024 + h * 64) * C_;
        for (int i = threadIdx.x; i < 4096; i += 256) {
            int d = i >> 6, r = i & 63;
            dst[(size_t)d * C_ + c0 + r] = t[d][r];
        }
    } else {
        int idx = g - 8960;
        int n0 = (idx & 15) * 64, k0 = (idx >> 4) * 64;
        for (int i = threadIdx.x; i < 4096; i += 256) {
            int r = i >> 6, c = i & 63;
            t[c][r] = f2b(Wproj[(size_t)(k0 + r) * C_ + n0 + c]);
        }
        __syncthreads();
        for (int i = threadIdx.x; i < 4096; i += 256) {
            int n = i >> 6, k = i & 63;
            WprojT[(size_t)(n0 + n) * 1024 + k0 + k] = t[n][k];
        }
    }
}

// ---------------- GEMM QK (R7-exact loop): 256x128, 32x32x16 MFMA, 2-stage dbuf ---------
// N = 2048 (Q|K sections only). Output stride ldc = 3072 into the QKV buffer.
__global__ __launch_bounds__(256, 2) void gemm_qk(const unsigned short* __restrict__ A,
                                                  const unsigned short* __restrict__ Bt,
                                                  unsigned short* __restrict__ Cout,
                                                  int M, int N, int K, int ldc) {
    constexpr int ABUF = 256 * 32;
    constexpr int BBUF = 128 * 32;
    __shared__ unsigned short smem[2 * ABUF + 2 * BBUF];   // 48 KB
    unsigned short* lA0 = smem;
    unsigned short* lB0 = smem + 2 * ABUF;

    int tid = threadIdx.x;
    int m0 = blockIdx.y * 256, n0 = blockIdx.x * 128;
    int lane = tid & 63, w = tid >> 6;
    int half = lane >> 5, l32 = lane & 31;
    int wm = w >> 1, wn = w & 1;

    const unsigned short* gA[4];
    int offA[4];
    #pragma unroll
    for (int j = 0; j < 4; j++) {
        int c = j * 256 + tid;
        int row = c >> 2;
        int col8 = ((c & 3) ^ ((row >> 1) & 3)) * 8;
        gA[j] = A + (size_t)(m0 + row) * K + col8;
        offA[j] = (j * 256 + w * 64) * 16;
    }
    const unsigned short* gB[2];
    int offB[2];
    #pragma unroll
    for (int j = 0; j < 2; j++) {
        int c = j * 256 + tid;
        int row = c >> 2;
        int col8 = ((c & 3) ^ ((row >> 1) & 3)) * 8;
        gB[j] = Bt + (size_t)(n0 + row) * K + col8;
        offB[j] = (j * 256 + w * 64) * 16;
    }

    int am[4], bn[2];
    #pragma unroll
    for (int mi = 0; mi < 4; mi++) am[mi] = wm * 128 + mi * 32 + l32;
    #pragma unroll
    for (int ni = 0; ni < 2; ni++) bn[ni] = wn * 64 + ni * 32 + l32;

    v16f acc[4][2];
    #pragma unroll
    for (int mi = 0; mi < 4; mi++)
        #pragma unroll
        for (int ni = 0; ni < 2; ni++)
            #pragma unroll
            for (int r = 0; r < 16; r++) acc[mi][ni][r] = 0.f;

    int ktiles = K >> 5;
    #pragma unroll
    for (int j = 0; j < 4; j++) GLOAD16(gA[j], (char*)lA0 + offA[j]);
    #pragma unroll
    for (int j = 0; j < 2; j++) GLOAD16(gB[j], (char*)lB0 + offB[j]);

    for (int it = 0; it < ktiles; it++) {
        int cur = it & 1, nxt = cur ^ 1;
        __asm__ volatile("s_waitcnt vmcnt(0)" ::: "memory");
        __asm__ volatile("s_barrier" ::: "memory");
        {
            int kn = (it + 1 < ktiles) ? (it + 1) * 32 : it * 32;
            #pragma unroll
            for (int j = 0; j < 4; j++) GLOAD16(gA[j] + kn, (char*)(lA0 + nxt * ABUF) + offA[j]);
            #pragma unroll
            for (int j = 0; j < 2; j++) GLOAD16(gB[j] + kn, (char*)(lB0 + nxt * BBUF) + offB[j]);
        }
        const unsigned short* bufA = lA0 + cur * ABUF;
        const unsigned short* bufB = lB0 + cur * BBUF;
        #pragma unroll
        for (int step = 0; step < 2; step++) {
            int g = step * 2 + half;
            v8s af[4], bf[2];
            #pragma unroll
            for (int mi = 0; mi < 4; mi++)
                af[mi] = *(const v8s*)&bufA[am[mi] * 32 + ((g ^ ((am[mi] >> 1) & 3)) * 8)];
            #pragma unroll
            for (int ni = 0; ni < 2; ni++)
                bf[ni] = *(const v8s*)&bufB[bn[ni] * 32 + ((g ^ ((bn[ni] >> 1) & 3)) * 8)];
            #pragma unroll
            for (int mi = 0; mi < 4; mi++)
                #pragma unroll
                for (int ni = 0; ni < 2; ni++)
                    acc[mi][ni] = __builtin_amdgcn_mfma_f32_32x32x16_bf16(af[mi], bf[ni], acc[mi][ni], 0, 0, 0);
        }
    }
    #pragma unroll
    for (int mi = 0; mi < 4; mi++) {
        #pragma unroll
        for (int ni = 0; ni < 2; ni++) {
            int col = n0 + wn * 64 + ni * 32 + l32;
            #pragma unroll
            for (int r = 0; r < 16; r++) {
                int row = m0 + wm * 128 + mi * 32 + (r & 3) + 8 * (r >> 2) + 4 * half;
                Cout[(size_t)row * ldc + col] = f2b(acc[mi][ni][r]);
            }
        }
    }
}

// ---------------- GEMM V: 128x128, 3-stage pipeline, XCD stripe; writes Vt transposed ---
__global__ __launch_bounds__(256, 3) void gemm_v(const unsigned short* __restrict__ A,
                                                 const unsigned short* __restrict__ Bt,
                                                 unsigned short* __restrict__ Vt,
                                                 int M, int N, int K) {
    constexpr int ABUF = 128 * 32;
    constexpr int BBUF = 128 * 32;
    __shared__ unsigned short lA[3 * ABUF];
    __shared__ unsigned short lB[3 * BBUF];

    int tid = threadIdx.x;
    int lane = tid & 63, w = tid >> 6;
    int half = lane >> 5, l32 = lane & 31;
    int wm = w >> 1, wn = w & 1;

    int g = blockIdx.x;
    int nbm = M / 128;
    int stripe = nbm >> 3;
    int xcd = g & 7, s = g >> 3;
    int m0 = (xcd * stripe + (s % stripe)) * 128;
    int n0 = (s / stripe) * 128;

    const unsigned short* gA[2];
    int offA[2];
    #pragma unroll
    for (int j = 0; j < 2; j++) {
        int c = j * 256 + tid;
        int row = c >> 2;
        int col8 = ((c & 3) ^ ((row >> 1) & 3)) * 8;
        gA[j] = A + (size_t)(m0 + row) * K + col8;
        offA[j] = (j * 256 + w * 64) * 16;
    }
    const unsigned short* gB[2];
    int offB[2];
    #pragma unroll
    for (int j = 0; j < 2; j++) {
        int c = j * 256 + tid;
        int row = c >> 2;
        int col8 = ((c & 3) ^ ((row >> 1) & 3)) * 8;
        gB[j] = Bt + (size_t)(n0 + row) * K + col8;
        offB[j] = (j * 256 + w * 64) * 16;
    }

    int am[2], bn[2];
    #pragma unroll
    for (int mi = 0; mi < 2; mi++) am[mi] = wm * 64 + mi * 32 + l32;
    #pragma unroll
    for (int ni = 0; ni < 2; ni++) bn[ni] = wn * 64 + ni * 32 + l32;

    v16f acc[2][2];
    #pragma unroll
    for (int mi = 0; mi < 2; mi++)
        #pragma unroll
        for (int ni = 0; ni < 2; ni++)
            #pragma unroll
            for (int r = 0; r < 16; r++) acc[mi][ni][r] = 0.f;

    int kt = K >> 5;
    #pragma unroll
    for (int j = 0; j < 2; j++) GLOAD16(gA[j], (char*)lA + offA[j]);
    #pragma unroll
    for (int j = 0; j < 2; j++) GLOAD16(gB[j], (char*)lB + offB[j]);
    #pragma unroll
    for (int j = 0; j < 2; j++) GLOAD16(gA[j] + 32, (char*)(lA + ABUF) + offA[j]);
    #pragma unroll
    for (int j = 0; j < 2; j++) GLOAD16(gB[j] + 32, (char*)(lB + BBUF) + offB[j]);

    int cur = 0;
    for (int it = 0; it < kt; it++) {
        int nx2 = cur + 2; if (nx2 >= 3) nx2 -= 3;
        __asm__ volatile("s_waitcnt vmcnt(4)" ::: "memory");
        __asm__ volatile("s_barrier" ::: "memory");
        {
            int kn = ((it + 2 < kt) ? it + 2 : kt - 1) << 5;
            #pragma unroll
            for (int j = 0; j < 2; j++) GLOAD16(gA[j] + kn, (char*)(lA + nx2 * ABUF) + offA[j]);
            #pragma unroll
            for (int j = 0; j < 2; j++) GLOAD16(gB[j] + kn, (char*)(lB + nx2 * BBUF) + offB[j]);
        }
        const unsigned short* bufA = lA + cur * ABUF;
        const unsigned short* bufB = lB + cur * BBUF;
        #pragma unroll
        for (int step = 0; step < 2; step++) {
            int gch = step * 2 + half;
            v8s af[2], bf[2];
            #pragma unroll
            for (int mi = 0; mi < 2; mi++)
                af[mi] = *(const v8s*)&bufA[am[mi] * 32 + ((gch ^ ((am[mi] >> 1) & 3)) * 8)];
            #pragma unroll
            for (int ni = 0; ni < 2; ni++)
                bf[ni] = *(const v8s*)&bufB[bn[ni] * 32 + ((gch ^ ((bn[ni] >> 1) & 3)) * 8)];
            #pragma unroll
            for (int mi = 0; mi < 2; mi++)
                #pragma unroll
                for (int ni = 0; ni < 2; ni++)
                    acc[mi][ni] = __builtin_amdgcn_mfma_f32_32x32x16_bf16(af[mi], bf[ni], acc[mi][ni], 0, 0, 0);
        }
        cur = cur + 1; if (cur >= 3) cur -= 3;
    }
    // epilogue: transpose 128(t) x 128(h*64+d) tile -> Vt[b,h,d,t]; 2 passes of 64 cols
    unsigned short* sT = lA;                 // 64 x 136 staging (reuse, 17.4 KB)
    int bB = m0 >> 10;
    int t0 = m0 & 1023;
    #pragma unroll
    for (int p = 0; p < 2; p++) {
        __syncthreads();
        if (wn == p) {
            #pragma unroll
            for (int mi = 0; mi < 2; mi++)
                #pragma unroll
                for (int ni = 0; ni < 2; ni++) {
                    int cl = ni * 32 + l32;
                    #pragma unroll
                    for (int r = 0; r < 16; r++) {
                        int rowl = wm * 64 + mi * 32 + (r & 3) + 8 * (r >> 2) + 4 * half;
                        sT[cl * 136 + rowl] = f2b(acc[mi][ni][r]);
                    }
                }
        }
        __syncthreads();
        #pragma unroll
        for (int j = 0; j < 4; j++) {
            int c = j * 256 + tid;
            int cl = c >> 4, ch = c & 15;    // 64 cols x 16 v8s-chunks of 128 rows
            int vcol = n0 + p * 64 + cl;     // = h*64 + d
            int hh = vcol >> 6, dd = vcol & 63;
            *(v8s*)&Vt[(((size_t)bB * 16 + hh) * 64 + dd) * T_ + t0 + ch * 8] =
                *(const v8s*)&sT[cl * 136 + ch * 8];
        }
    }
}

// ---------------- GEMM proj (unchanged): 128x128, 3-stage pipeline, XCD stripe ------
__global__ __launch_bounds__(256, 3) void gemm_proj(const unsigned short* __restrict__ A,
                                                    const unsigned short* __restrict__ Bt,
                                                    float* __restrict__ Cout,
                                                    const float* __restrict__ bias,
                                                    int M, int N, int K) {
    constexpr int ABUF = 128 * 32;
    constexpr int BBUF = 128 * 32;
    __shared__ unsigned short lA[3 * ABUF];
    __shared__ unsigned short lB[3 * BBUF];

    int tid = threadIdx.x;
    int lane = tid & 63, w = tid >> 6;
    int half = lane >> 5, l32 = lane & 31;
    int wm = w >> 1, wn = w & 1;

    int g = blockIdx.x;
    int nbm = M / 128;
    int stripe = nbm >> 3;
    int xcd = g & 7, s = g >> 3;
    int m0 = (xcd * stripe + (s % stripe)) * 128;
    int n0 = (s / stripe) * 128;

    const unsigned short* gA[2];
    int offA[2];
    #pragma unroll
    for (int j = 0; j < 2; j++) {
        int c = j * 256 + tid;
        int row = c >> 2;
        int col8 = ((c & 3) ^ ((row >> 1) & 3)) * 8;
        gA[j] = A + (size_t)(m0 + row) * K + col8;
        offA[j] = (j * 256 + w * 64) * 16;
    }
    const unsigned short* gB[2];
    int offB[2];
    #pragma unroll
    for (int j = 0; j < 2; j++) {
        int c = j * 256 + tid;
        int row = c >> 2;
        int col8 = ((c & 3) ^ ((row >> 1) & 3)) * 8;
        gB[j] = Bt + (size_t)(n0 + row) * K + col8;
        offB[j] = (j * 256 + w * 64) * 16;
    }

    int am[2], bn[2];
    #pragma unroll
    for (int mi = 0; mi < 2; mi++) am[mi] = wm * 64 + mi * 32 + l32;
    #pragma unroll
    for (int ni = 0; ni < 2; ni++) bn[ni] = wn * 64 + ni * 32 + l32;

    v16f acc[2][2];
    #pragma unroll
    for (int mi = 0; mi < 2; mi++)
        #pragma unroll
        for (int ni = 0; ni < 2; ni++)
            #pragma unroll
            for (int r = 0; r < 16; r++) acc[mi][ni][r] = 0.f;

    int kt = K >> 5;
    #pragma unroll
    for (int j = 0; j < 2; j++) GLOAD16(gA[j], (char*)lA + offA[j]);
    #pragma unroll
    for (int j = 0; j < 2; j++) GLOAD16(gB[j], (char*)lB + offB[j]);
    #pragma unroll
    for (int j = 0; j < 2; j++) GLOAD16(gA[j] + 32, (char*)(lA + ABUF) + offA[j]);
    #pragma unroll
    for (int j = 0; j < 2; j++) GLOAD16(gB[j] + 32, (char*)(lB + BBUF) + offB[j]);

    int cur = 0;
    for (int it = 0; it < kt; it++) {
        int nx2 = cur + 2; if (nx2 >= 3) nx2 -= 3;
        __asm__ volatile("s_waitcnt vmcnt(4)" ::: "memory");
        __asm__ volatile("s_barrier" ::: "memory");
        {
            int kn = ((it + 2 < kt) ? it + 2 : kt - 1) << 5;
            #pragma unroll
            for (int j = 0; j < 2; j++) GLOAD16(gA[j] + kn, (char*)(lA + nx2 * ABUF) + offA[j]);
            #pragma unroll
            for (int j = 0; j < 2; j++) GLOAD16(gB[j] + kn, (char*)(lB + nx2 * BBUF) + offB[j]);
        }
        const unsigned short* bufA = lA + cur * ABUF;
        const unsigned short* bufB = lB + cur * BBUF;
        #pragma unroll
        for (int step = 0; step < 2; step++) {
            int gch = step * 2 + half;
            v8s af[2], bf[2];
            #pragma unroll
            for (int mi = 0; mi < 2; mi++)
                af[mi] = *(const v8s*)&bufA[am[mi] * 32 + ((gch ^ ((am[mi] >> 1) & 3)) * 8)];
            #pragma unroll
            for (int ni = 0; ni < 2; ni++)
                bf[ni] = *(const v8s*)&bufB[bn[ni] * 32 + ((gch ^ ((bn[ni] >> 1) & 3)) * 8)];
            #pragma unroll
            for (int mi = 0; mi < 2; mi++)
                #pragma unroll
                for (int ni = 0; ni < 2; ni++)
                    acc[mi][ni] = __builtin_amdgcn_mfma_f32_32x32x16_bf16(af[mi], bf[ni], acc[mi][ni], 0, 0, 0);
        }
        cur = cur + 1; if (cur >= 3) cur -= 3;
    }
    #pragma unroll
    for (int mi = 0; mi < 2; mi++) {
        #pragma unroll
        for (int ni = 0; ni < 2; ni++) {
            int col = n0 + wn * 64 + ni * 32 + l32;
            #pragma unroll
            for (int r = 0; r < 16; r++) {
                int row = m0 + wm * 64 + mi * 32 + (r & 3) + 8 * (r >> 2) + 4 * half;
                Cout[(size_t)row * N + col] = acc[mi][ni][r] + bias[col];
            }
        }
    }
}

// ---------------- Flash attention v5 (unchanged): S-transposed, register-resident P ------
__global__ __launch_bounds__(256) void attn_kernel(const unsigned short* __restrict__ QKV,
                                                   const unsigned short* __restrict__ Vt,
                                                   unsigned short* __restrict__ Ob) {
    int bh = blockIdx.x;
    int qt = 7 - blockIdx.y;
    int b = bh >> 4, h = bh & 15;
    int tid = threadIdx.x, lane = tid & 63, w = tid >> 6;
    int quad = lane >> 4, l16 = lane & 15;
    int qg0 = qt * 128 + w * 32;

    __shared__ unsigned short lK[2][2][64][32];
    __shared__ unsigned short lV[2][64][32];

    v8s aq[2][2];
    #pragma unroll
    for (int st = 0; st < 2; st++) {
        const unsigned short* qp = QKV + (size_t)(b * T_ + qg0 + st * 16 + l16) * QKVLD + h * 64;
        aq[st][0] = *(const v8s*)(qp + quad * 8);
        aq[st][1] = *(const v8s*)(qp + 32 + quad * 8);
    }

    const unsigned short* gK[2];
    const unsigned short* gV[2];
    int ldsOff[2];
    #pragma unroll
    for (int j = 0; j < 2; j++) {
        int c = j * 256 + tid;
        int halfp = c >> 8, row = (c >> 2) & 63;
        int col8 = ((c & 3) ^ ((row >> 1) & 3)) * 8;
        gK[j] = QKV + (size_t)(b * T_ + row) * QKVLD + 1024 + h * 64 + halfp * 32 + col8;
        gV[j] = Vt + ((size_t)bh * 64 + row) * T_ + halfp * 32 + col8;
        ldsOff[j] = (j * 256 + w * 64) * 16;
    }
    int rcol = (quad ^ ((l16 >> 1) & 3)) * 8;

    v4f accO[2][4];
    float lsum[2] = {0.f, 0.f};
    #pragma unroll
    for (int st = 0; st < 2; st++)
        #pragma unroll
        for (int i = 0; i < 4; i++) accO[st][i] = (v4f){0.f, 0.f, 0.f, 0.f};

    int ntiles = 2 * qt + 2;
    const float SC = 0.1803368801f;

    #pragma unroll
    for (int j = 0; j < 2; j++)
        GLOAD16(gK[j], (char*)&lK[0][0][0][0] + ldsOff[j]);

    for (int it = 0; it < ntiles; it++) {
        int cur = it & 1, nxt = cur ^ 1;
        int s0 = it * 64;
        __asm__ volatile("s_waitcnt vmcnt(0)" ::: "memory");
        __asm__ volatile("s_barrier" ::: "memory");
        #pragma unroll
        for (int j = 0; j < 2; j++)
            GLOAD16(gV[j] + s0, (char*)&lV[0][0][0] + ldsOff[j]);
        __asm__ volatile("" ::: "memory");
        {
            int itn = (it + 1 < ntiles) ? it + 1 : it;
            size_t koff = (size_t)itn * 64 * QKVLD;
            #pragma unroll
            for (int j = 0; j < 2; j++)
                GLOAD16(gK[j] + koff, (char*)&lK[nxt][0][0][0] + ldsOff[j]);
        }
        bool act0 = (qg0 + 15 >= s0);
        bool act1 = (qg0 + 31 >= s0);
        v4s pP[2][4];
        if (act1) {
            v4f sf[2][4];
            #pragma unroll
            for (int nt = 0; nt < 4; nt++) {
                v8s bk0 = *(const v8s*)&lK[cur][0][nt * 16 + l16][rcol];
                v8s bk1 = *(const v8s*)&lK[cur][1][nt * 16 + l16][rcol];
                v4f a1 = (v4f){0.f, 0.f, 0.f, 0.f};
                a1 = MFMA32(bk0, aq[1][0], a1);
                a1 = MFMA32(bk1, aq[1][1], a1);
                sf[1][nt] = a1;
                if (act0) {
                    v4f a0 = (v4f){0.f, 0.f, 0.f, 0.f};
                    a0 = MFMA32(bk0, aq[0][0], a0);
                    a0 = MFMA32(bk1, aq[0][1], a0);
                    sf[0][nt] = a0;
                }
            }
            bool diag = (it >= ntiles - 2);
            #pragma unroll
            for (int st = 0; st < 2; st++) {
                if (st == 0 && !act0) continue;
                int qg = qg0 + st * 16 + l16;
                #pragma unroll
                for (int nt = 0; nt < 4; nt++) {
                    float p[4];
                    #pragma unroll
                    for (int r = 0; r < 4; r++) {
                        if (diag) {
                            int sg = s0 + nt * 16 + quad * 4 + r;
                            p[r] = (sg > qg) ? 0.f : fexp2(sf[st][nt][r] * SC);
                        } else {
                            p[r] = fexp2(sf[st][nt][r] * SC);
                        }
                        lsum[st] += p[r];
                    }
                    pP[st][nt] = pack4(p[0], p[1], p[2], p[3]);
                }
            }
        }
        __asm__ volatile("s_waitcnt vmcnt(2)" ::: "memory");
        __asm__ volatile("s_barrier" ::: "memory");
        if (act1) {
            #pragma unroll
            for (int kb = 0; kb < 4; kb++) {
                int sc_ = kb >> 1;
                int ccg = (kb & 1) * 2 + (quad >> 1);
                #pragma unroll
                for (int dt = 0; dt < 4; dt++) {
                    int d = dt * 16 + l16;
                    int ccp = ccg ^ ((l16 >> 1) & 3);
                    v4s bv = *(const v4s*)&lV[sc_][d][ccp * 8 + (quad & 1) * 4];
                    accO[1][dt] = MFMA16(pP[1][kb], bv, accO[1][dt]);
                    if (act0) accO[0][dt] = MFMA16(pP[0][kb], bv, accO[0][dt]);
                }
            }
        }
    }
    #pragma unroll
    for (int st = 0; st < 2; st++) {
        float ls = lsum[st];
        ls += __shfl_xor(ls, 16, 64);
        ls += __shfl_xor(ls, 32, 64);
        #pragma unroll
        for (int r = 0; r < 4; r++) {
            float lq = __shfl(ls, quad * 4 + r, 64);
            float inv = 1.0f / lq;
            int q = qg0 + st * 16 + quad * 4 + r;
            #pragma unroll
            for (int dt = 0; dt < 4; dt++) {
                int d = dt * 16 + l16;
                Ob[(size_t)(b * T_ + q) * (H_ * D_) + h * 64 + d] = f2b(accO[st][dt][r] * inv);
            }
        }
    }
}

extern "C" void kernel_launch(void* const* d_in, const int* in_sizes, int n_in,
                              void* d_out, int out_size, void* d_ws, size_t ws_size,
                              hipStream_t stream) {
    const float* x     = (const float*)d_in[0];
    const float* Wq    = (const float*)d_in[1];
    const float* Wk    = (const float*)d_in[2];
    const float* Wv    = (const float*)d_in[3];
    const float* Wproj = (const float*)d_in[4];
    const float* bproj = (const float*)d_in[5];
    float* out = (float*)d_out;

    char* ws = (char*)d_ws;
    unsigned short* xb     = (unsigned short*)ws;                          // 16 MB  [8192][1024]
    unsigned short* WqkvT  = (unsigned short*)(ws + 16777216);             // 6 MB   [3072][1024]
    unsigned short* WprojT = (unsigned short*)(ws + 23068672);             // 2 MB   [1024][1024]
    unsigned short* QKV    = (unsigned short*)(ws + 25165824);             // 48 MB  [8192][3072] (Q|K used)
    unsigned short* Vt     = (unsigned short*)(ws + 75497472);             // 16 MB  [B,H,D,T]
    unsigned short* Ob     = (unsigned short*)(ws + 92274688);             // 16 MB  [8192][1024]

    prep_kernel<<<dim3(9216), dim3(256), 0, stream>>>(x, Wq, Wk, Wv, Wproj, xb, WqkvT, WprojT);
    gemm_qk<<<dim3(16, 32), dim3(256), 0, stream>>>(xb, WqkvT, QKV, 8192, 2048, 1024, QKVLD);
    gemm_v<<<dim3(512), dim3(256), 0, stream>>>(xb, WqkvT + (size_t)2048 * 1024, Vt, 8192, 1024, 1024);
    attn_kernel<<<dim3(128, 8), dim3(256), 0, stream>>>(QKV, Vt, Ob);
    gemm_proj<<<dim3(512), dim3(256), 0, stream>>>(Ob, WprojT, out, bproj, 8192, 1024, 1024);
}